// Round 6
// baseline (85.745 us; speedup 1.0000x reference)
//
#include <hip/hip_runtime.h>

#define NN     4096
#define TT     3
#define DD     20
#define EE     131072
#define ADIM   128
#define NEG    0.2f
#define NINST  (TT * EE)               // 393216 edge instances
#define TRI    ((NN * (NN + 1)) / 2)   // 8390656 unordered-pair slots
#define TRIW   ((TRI + 7) / 8)         // 1048832 mask words (4 bits/slot)
#define TRIW4  ((TRIW + 3) / 4)        // 262208 uint4
#define CAP    512                     // entries per row (mean ~181, max ~250)
#define CSTR   16                      // cnt stride in u32 -> one 64B line per row

// ---- k0: zero mask + counters, init scores s0 = inputs@lin_w.T + lin_b ------
__global__ __launch_bounds__(256) void k_init(uint4* __restrict__ mask4,
                                              unsigned int* __restrict__ cnt,
                                              const float* __restrict__ inputs,
                                              const float* __restrict__ lin_w,
                                              const float* __restrict__ lin_b,
                                              float* __restrict__ s0) {
    int tid = threadIdx.x, bid = blockIdx.x;
    int gid = bid * 256 + tid;
    for (int i = gid; i < TRIW4; i += 1024 * 256)
        mask4[i] = make_uint4(0u, 0u, 0u, 0u);
    uint4* cnt4 = (uint4*)cnt;                     // NN*CSTR u32 = 16384 uint4
    for (int i = gid; i < NN * CSTR / 4; i += 1024 * 256)
        cnt4[i] = make_uint4(0u, 0u, 0u, 0u);

    int wid = tid >> 6, lane = tid & 63;
    int row = bid * 4 + wid;                       // 1024 blocks * 4 waves = 4096 rows
    const float* rp = inputs + row * ADIM;
    float v = rp[lane] * lin_w[lane] + rp[lane + 64] * lin_w[lane + 64];
    #pragma unroll
    for (int off = 32; off > 0; off >>= 1) v += __shfl_down(v, off);
    if (lane == 0) s0[row] = v + lin_b[0];
}

// ---- k1: scatter types into nibble-mask + inline CSR build -------------------
// The thread whose atomicOr finds the pair's nibble EMPTY is the pair's unique
// owner (L2 atomics on one address serialize) and appends j to both rows.
__global__ __launch_bounds__(256) void k_scatter(const int* __restrict__ el,
                                                 unsigned int* __restrict__ mask,
                                                 unsigned int* __restrict__ cnt,
                                                 unsigned short* __restrict__ entries) {
    int i = blockIdx.x * 256 + threadIdx.x;        // exactly NINST threads
    int t = i >> 17;                               // EE = 2^17
    int e = i & (EE - 1);
    unsigned int src = (unsigned int)el[(t * 2) * EE + e];
    unsigned int tgt = (unsigned int)el[(t * 2 + 1) * EE + e];
    unsigned int lo = min(src, tgt), hi = max(src, tgt);
    unsigned int slot = ((hi * (hi + 1)) >> 1) + lo;
    unsigned int nsh = (slot & 7u) << 2;
    unsigned int old = atomicOr(&mask[slot >> 3], 1u << (nsh + (unsigned int)t));
    if (((old >> nsh) & 0xFu) == 0u) {             // first bit ever for this pair
        unsigned int idx = atomicAdd(&cnt[lo * CSTR], 1u);
        if (idx < CAP) entries[lo * CAP + idx] = (unsigned short)hi;
        if (lo != hi) {
            unsigned int idx2 = atomicAdd(&cnt[hi * CSTR], 1u);
            if (idx2 < CAP) entries[hi * CAP + idx2] = (unsigned short)lo;
        }
    }
}

// ---- k2: one GNN layer over CSR (both heads + S-sum fused), row per wave ----
__global__ __launch_bounds__(256) void k_layer(const unsigned int* __restrict__ cnt,
                                               const unsigned short* __restrict__ entries,
                                               const unsigned int* __restrict__ mask,
                                               const float* __restrict__ s_in,
                                               const float* __restrict__ att_w,
                                               const float* __restrict__ edge_emb,
                                               float* __restrict__ s_out,
                                               int layer) {
    __shared__ float lut0[8], lut1[8], wc[4], Sred[4];
    int tid = threadIdx.x;

    if (tid < 16) {
        int h = tid >> 3, m = tid & 7;
        const float* w = att_w + (layer * 2 + h) * (DD + 2);
        float e0 = 0.f, e1 = 0.f, e2 = 0.f;
        #pragma unroll
        for (int d = 0; d < DD; d++) {
            float wd = w[1 + d];
            e0 += edge_emb[0 * DD + d] * wd;
            e1 += edge_emb[1 * DD + d] * wd;
            e2 += edge_emb[2 * DD + d] * wd;
        }
        float l = (m & 1 ? e0 : 0.f) + (m & 2 ? e1 : 0.f) + (m & 4 ? e2 : 0.f);
        if (h) lut1[m] = l; else lut0[m] = l;
        if (m == 0) { wc[h] = w[0]; wc[2 + h] = w[DD + 1]; }
    }

    // Block-level S = sum(s_in) (16 KB, cache-resident, deterministic).
    float ps = 0.f;
    for (int j = tid; j < NN; j += 256) ps += s_in[j];
    #pragma unroll
    for (int off = 32; off > 0; off >>= 1) ps += __shfl_down(ps, off);
    int wid = tid >> 6, lane = tid & 63;
    if (lane == 0) Sred[wid] = ps;
    __syncthreads();
    float S = Sred[0] + Sred[1] + Sred[2] + Sred[3];

    int row = blockIdx.x * 4 + wid;
    float si = s_in[row];
    float a0 = wc[0] * si, a1 = wc[1] * si;
    float b0 = wc[2],      b1 = wc[3];
    unsigned int n = min(cnt[row * CSTR], (unsigned int)CAP);
    const unsigned short* ent = entries + (size_t)row * CAP;
    unsigned int urow = (unsigned int)row;

    float num0 = 0.f, den0 = 0.f, num1 = 0.f, den1 = 0.f;
    for (unsigned int i = lane; i < n; i += 64) {
        unsigned int j = ent[i];
        unsigned int lo = min(urow, j), hi = max(urow, j);
        unsigned int slot = ((hi * (hi + 1)) >> 1) + lo;
        unsigned int nib = (mask[slot >> 3] >> ((slot & 7u) << 2)) & 0xFu;
        float c  = (float)__popc(nib);
        float sj = s_in[j];
        float l0 = c * (a0 + b0 * sj) + lut0[nib];
        l0 = (l0 > 0.f) ? l0 : NEG * l0;
        float x0 = __expf(l0) - 1.0f;
        num0 += x0 * sj; den0 += x0;
        float l1 = c * (a1 + b1 * sj) + lut1[nib];
        l1 = (l1 > 0.f) ? l1 : NEG * l1;
        float x1 = __expf(l1) - 1.0f;
        num1 += x1 * sj; den1 += x1;
    }

    #pragma unroll
    for (int off = 32; off > 0; off >>= 1) {
        num0 += __shfl_down(num0, off); den0 += __shfl_down(den0, off);
        num1 += __shfl_down(num1, off); den1 += __shfl_down(den1, off);
    }
    if (lane == 0) {
        float o0 = (S + num0) / ((float)NN + den0);
        float o1 = (S + num1) / ((float)NN + den1);
        s_out[row] = 0.5f * (o0 + o1);
    }
}

// ---- host-side launcher ------------------------------------------------------
extern "C" void kernel_launch(void* const* d_in, const int* in_sizes, int n_in,
                              void* d_out, int out_size, void* d_ws, size_t ws_size,
                              hipStream_t stream) {
    const float* inputs   = (const float*)d_in[0];
    const float* lin_w    = (const float*)d_in[1];
    const float* lin_b    = (const float*)d_in[2];
    const float* edge_emb = (const float*)d_in[3];
    const float* att_w    = (const float*)d_in[4];
    const int*   el       = (const int*)d_in[5];
    float* out = (float*)d_out;

    char* ws = (char*)d_ws;
    unsigned int*   mask    = (unsigned int*)ws;                          // 4.2 MB
    unsigned int*   cnt     = (unsigned int*)(ws + 4456448);              // 256 KB (padded)
    unsigned short* entries = (unsigned short*)(ws + 4718592);            // 4 MB
    float*          s0      = (float*)(ws + 8912896);                     // 16 KB
    float*          s1      = (float*)(ws + 8929280);                     // 16 KB

    k_init   <<<1024, 256, 0, stream>>>((uint4*)mask, cnt, inputs, lin_w, lin_b, s0);
    k_scatter<<<NINST / 256, 256, 0, stream>>>(el, mask, cnt, entries);
    k_layer  <<<1024, 256, 0, stream>>>(cnt, entries, mask, s0, att_w, edge_emb, s1, 0);
    k_layer  <<<1024, 256, 0, stream>>>(cnt, entries, mask, s1, att_w, edge_emb, out, 1);
}

// Round 7
// 66.784 us; speedup vs baseline: 1.2839x; 1.2839x over previous
//
#include <hip/hip_runtime.h>

#define NN     4096
#define TT     3
#define DD     20
#define EE     131072
#define ADIM   128
#define NEG    0.2f
#define NINST  (TT * EE)               // 393216 edge instances
#define WPR    512                     // u32 mask words per row (nibble per col)
#define MASKW  (NN * WPR)              // 2M words = 8 MB
#define CAP    512                     // entries per row (mean ~181, max ~250)

// ---- k0: zero 8 MB mask + init scores s0 = inputs@lin_w.T + lin_b -----------
__global__ __launch_bounds__(256) void k_init(uint4* __restrict__ mask4,
                                              const float* __restrict__ inputs,
                                              const float* __restrict__ lin_w,
                                              const float* __restrict__ lin_b,
                                              float* __restrict__ s0) {
    int tid = threadIdx.x, bid = blockIdx.x;
    int gid = bid * 256 + tid;                     // 262144 threads, 2 uint4 each
    mask4[gid]          = make_uint4(0u, 0u, 0u, 0u);
    mask4[gid + 262144] = make_uint4(0u, 0u, 0u, 0u);

    int wid = tid >> 6, lane = tid & 63;
    int row = bid * 4 + wid;                       // 1024 blocks * 4 waves = 4096 rows
    const float* rp = inputs + row * ADIM;
    float v = rp[lane] * lin_w[lane] + rp[lane + 64] * lin_w[lane + 64];
    #pragma unroll
    for (int off = 32; off > 0; off >>= 1) v += __shfl_down(v, off);
    if (lane == 0) s0[row] = v + lin_b[0];
}

// ---- k1: fire-and-forget scatter of type bits into symmetric nibble mask ----
__global__ __launch_bounds__(256) void k_scatter(const int* __restrict__ el,
                                                 unsigned int* __restrict__ mask) {
    int i = blockIdx.x * 256 + threadIdx.x;        // exactly NINST threads
    int t = i >> 17;                               // EE = 2^17
    int e = i & (EE - 1);
    unsigned int src = (unsigned int)el[(t * 2) * EE + e];
    unsigned int tgt = (unsigned int)el[(t * 2 + 1) * EE + e];
    unsigned int p1 = src * NN + tgt;
    unsigned int p2 = tgt * NN + src;
    atomicOr(&mask[p1 >> 3], 1u << (((p1 & 7u) << 2) + (unsigned)t));
    if (p1 != p2)
        atomicOr(&mask[p2 >> 3], 1u << (((p2 & 7u) << 2) + (unsigned)t));
}

// ---- k2: dense row-scan -> packed CSR, no atomics, wave per row -------------
__global__ __launch_bounds__(256) void k_build(const unsigned int* __restrict__ mask,
                                               unsigned int* __restrict__ cnt,
                                               unsigned short* __restrict__ entries) {
    int tid = threadIdx.x;
    int wid = tid >> 6, lane = tid & 63;
    int row = blockIdx.x * 4 + wid;                // 1024 blocks * 4 waves
    const unsigned int* mrow = mask + (size_t)row * WPR;
    unsigned short* erow = entries + (size_t)row * CAP;

    unsigned int base = 0;
    #pragma unroll
    for (int k = 0; k < 8; k++) {
        unsigned int w = mrow[k * 64 + lane];
        // count nonzero nibbles: OR nibble bits into bit0 of each nibble
        unsigned int y = w | (w >> 1); y |= (y >> 2); y &= 0x11111111u;
        unsigned int c = __popc(y);
        // wave-inclusive scan of c
        unsigned int p = c;
        #pragma unroll
        for (int off = 1; off < 64; off <<= 1) {
            unsigned int v = __shfl_up(p, off);
            if (lane >= off) p += v;
        }
        unsigned int pos = base + (p - c);         // exclusive prefix
        if (w) {
            int jb = (k * 64 + lane) << 3;
            #pragma unroll
            for (int kk = 0; kk < 8; kk++) {
                unsigned int nib = (w >> (kk * 4)) & 0xFu;
                if (nib) erow[pos++] = (unsigned short)((jb + kk) | (nib << 12));
            }
        }
        base += __shfl(p, 63);                     // wave total this iteration
    }
    if (lane == 0) cnt[row] = base;
}

// ---- k3: one GNN layer over CSR (both heads + S-sum fused), row per wave ----
__global__ __launch_bounds__(256) void k_layer(const unsigned int* __restrict__ cnt,
                                               const unsigned short* __restrict__ entries,
                                               const float* __restrict__ s_in,
                                               const float* __restrict__ att_w,
                                               const float* __restrict__ edge_emb,
                                               float* __restrict__ s_out,
                                               int layer) {
    __shared__ float lut0[8], lut1[8], wc[4], Sred[4];
    int tid = threadIdx.x;

    if (tid < 16) {
        int h = tid >> 3, m = tid & 7;
        const float* w = att_w + (layer * 2 + h) * (DD + 2);
        float e0 = 0.f, e1 = 0.f, e2 = 0.f;
        #pragma unroll
        for (int d = 0; d < DD; d++) {
            float wd = w[1 + d];
            e0 += edge_emb[0 * DD + d] * wd;
            e1 += edge_emb[1 * DD + d] * wd;
            e2 += edge_emb[2 * DD + d] * wd;
        }
        float l = (m & 1 ? e0 : 0.f) + (m & 2 ? e1 : 0.f) + (m & 4 ? e2 : 0.f);
        if (h) lut1[m] = l; else lut0[m] = l;
        if (m == 0) { wc[h] = w[0]; wc[2 + h] = w[DD + 1]; }
    }

    // Block-level S = sum(s_in) (16 KB, cache-resident, deterministic).
    float ps = 0.f;
    for (int j = tid; j < NN; j += 256) ps += s_in[j];
    #pragma unroll
    for (int off = 32; off > 0; off >>= 1) ps += __shfl_down(ps, off);
    int wid = tid >> 6, lane = tid & 63;
    if (lane == 0) Sred[wid] = ps;
    __syncthreads();
    float S = Sred[0] + Sred[1] + Sred[2] + Sred[3];

    int row = blockIdx.x * 4 + wid;
    float si = s_in[row];
    float a0 = wc[0] * si, a1 = wc[1] * si;
    float b0 = wc[2],      b1 = wc[3];
    unsigned int n = cnt[row];
    const unsigned short* ent = entries + (size_t)row * CAP;

    float num0 = 0.f, den0 = 0.f, num1 = 0.f, den1 = 0.f;
    for (unsigned int i = lane; i < n; i += 64) {
        unsigned int v = ent[i];
        unsigned int j = v & 0xFFFu, nib = v >> 12;
        float c  = (float)__popc(nib);
        float sj = s_in[j];
        float l0 = c * (a0 + b0 * sj) + lut0[nib];
        l0 = (l0 > 0.f) ? l0 : NEG * l0;
        float x0 = __expf(l0) - 1.0f;
        num0 += x0 * sj; den0 += x0;
        float l1 = c * (a1 + b1 * sj) + lut1[nib];
        l1 = (l1 > 0.f) ? l1 : NEG * l1;
        float x1 = __expf(l1) - 1.0f;
        num1 += x1 * sj; den1 += x1;
    }

    #pragma unroll
    for (int off = 32; off > 0; off >>= 1) {
        num0 += __shfl_down(num0, off); den0 += __shfl_down(den0, off);
        num1 += __shfl_down(num1, off); den1 += __shfl_down(den1, off);
    }
    if (lane == 0) {
        float o0 = (S + num0) / ((float)NN + den0);
        float o1 = (S + num1) / ((float)NN + den1);
        s_out[row] = 0.5f * (o0 + o1);
    }
}

// ---- host-side launcher ------------------------------------------------------
extern "C" void kernel_launch(void* const* d_in, const int* in_sizes, int n_in,
                              void* d_out, int out_size, void* d_ws, size_t ws_size,
                              hipStream_t stream) {
    const float* inputs   = (const float*)d_in[0];
    const float* lin_w    = (const float*)d_in[1];
    const float* lin_b    = (const float*)d_in[2];
    const float* edge_emb = (const float*)d_in[3];
    const float* att_w    = (const float*)d_in[4];
    const int*   el       = (const int*)d_in[5];
    float* out = (float*)d_out;

    char* ws = (char*)d_ws;
    unsigned int*   mask    = (unsigned int*)ws;                          // 8 MB
    unsigned short* entries = (unsigned short*)(ws + 8388608);            // 4 MB
    unsigned int*   cnt     = (unsigned int*)(ws + 12582912);             // 16 KB
    float*          s0      = (float*)(ws + 12599296);                    // 16 KB
    float*          s1      = (float*)(ws + 12615680);                    // 16 KB

    k_init   <<<1024, 256, 0, stream>>>((uint4*)mask, inputs, lin_w, lin_b, s0);
    k_scatter<<<NINST / 256, 256, 0, stream>>>(el, mask);
    k_build  <<<1024, 256, 0, stream>>>(mask, cnt, entries);
    k_layer  <<<1024, 256, 0, stream>>>(cnt, entries, s0, att_w, edge_emb, s1, 0);
    k_layer  <<<1024, 256, 0, stream>>>(cnt, entries, s1, att_w, edge_emb, out, 1);
}